// Round 5
// baseline (498.867 us; speedup 1.0000x reference)
//
#include <hip/hip_runtime.h>

// GraphConv 3-hop SpMM, CSR rebuilt per call; 4 rows/wave float4 hop kernel.
// out layout: [N_NODES, 4, 64] fp32 (flat = node*256 + hop*64 + j).
// R5: replace hipMemsetAsync(cnt) -- rocclr small-fill ran at 6.7 GB/s,
//     300us/replay = 60% of budget -- with a hand-rolled zero kernel.

#define DFEAT 64
#define SCAN_TPB 256
#define SCAN_EPB 2048  // 8 elements per thread

typedef float f32x4 __attribute__((ext_vector_type(4)));  // native vec for NT store

// ---------- zero the count array (int4 stores) ----------
__global__ void gc_zero(int4* __restrict__ p, int n4) {
    int i = blockIdx.x * blockDim.x + threadIdx.x;
    if (i < n4) p[i] = make_int4(0, 0, 0, 0);
}

// ---------- init: write hop-0 slice from embeddings ----------
__global__ void gc_init_hop0(const float4* __restrict__ user4,
                             const float4* __restrict__ item4,
                             float4* __restrict__ out4,
                             int n_users, int n_nodes) {
    int tid = blockIdx.x * blockDim.x + threadIdx.x;
    if (tid >= n_nodes * 16) return;
    int node = tid >> 4;
    int q = tid & 15;
    float4 v = (node < n_users) ? user4[(size_t)node * 16 + q]
                                : item4[(size_t)(node - n_users) * 16 + q];
    out4[(size_t)node * 64 + q] = v;   // hop 0 slot
}

// ---------- CSR build ----------
__global__ void gc_hist(const int* __restrict__ row, int* __restrict__ cnt, int nnz) {
    int i = blockIdx.x * blockDim.x + threadIdx.x;
    if (i < nnz) atomicAdd(&cnt[row[i]], 1);
}

__global__ void gc_scan1(const int* __restrict__ cnt, int* __restrict__ excl,
                         int* __restrict__ bsums, int n) {
    __shared__ int lds[SCAN_TPB];
    int t = threadIdx.x;
    int base = blockIdx.x * SCAN_EPB + t * 8;
    int v[8];
    int s = 0;
    for (int k = 0; k < 8; ++k) {
        int idx = base + k;
        v[k] = (idx < n) ? cnt[idx] : 0;
        s += v[k];
    }
    lds[t] = s;
    __syncthreads();
    for (int off = 1; off < SCAN_TPB; off <<= 1) {
        int u = (t >= off) ? lds[t - off] : 0;
        __syncthreads();
        lds[t] += u;
        __syncthreads();
    }
    int run = (t > 0) ? lds[t - 1] : 0;
    for (int k = 0; k < 8; ++k) {
        int idx = base + k;
        if (idx < n) excl[idx] = run;
        run += v[k];
    }
    if (t == SCAN_TPB - 1) bsums[blockIdx.x] = lds[SCAN_TPB - 1];
}

__global__ void gc_scan2(int* __restrict__ bsums, int nb) {
    __shared__ int lds[SCAN_TPB];
    int t = threadIdx.x;
    int v = (t < nb) ? bsums[t] : 0;
    lds[t] = v;
    __syncthreads();
    for (int off = 1; off < SCAN_TPB; off <<= 1) {
        int u = (t >= off) ? lds[t - off] : 0;
        __syncthreads();
        lds[t] += u;
        __syncthreads();
    }
    int excl = (t > 0) ? lds[t - 1] : 0;
    if (t < nb) bsums[t] = excl;
}

__global__ void gc_scan3(int* __restrict__ excl, const int* __restrict__ bsums,
                         int* __restrict__ row_ptr, int* __restrict__ cursor,
                         int n, int nnz) {
    int i = blockIdx.x * blockDim.x + threadIdx.x;
    if (i < n) {
        int v = excl[i] + bsums[i / SCAN_EPB];
        row_ptr[i] = v;
        cursor[i] = v;
    }
    if (i == 0) row_ptr[n] = nnz;
}

// Scatter edges into CSR order, packing (col,val) into float2 (8B store).
__global__ void gc_scatter(const int* __restrict__ row, const int* __restrict__ col,
                           const float* __restrict__ val,
                           int* __restrict__ cursor, float2* __restrict__ edges,
                           int nnz) {
    int i = blockIdx.x * blockDim.x + threadIdx.x;
    if (i >= nnz) return;
    int r = row[i];
    int pos = atomicAdd(&cursor[r], 1);
    edges[pos] = make_float2(__int_as_float(col[i]), val[i]);
}

// ---------- hop: 16 lanes (float4 each) per row; 4 rows per wave ----------
__global__ void gc_spmm_csr4(const int* __restrict__ rp,
                             const float2* __restrict__ edges,
                             float* __restrict__ out, int hop, int n_nodes) {
    int tid = blockIdx.x * blockDim.x + threadIdx.x;
    int q = tid & 15;           // float4 quad within the row
    int r = tid >> 4;           // one row per 16 lanes
    if (r >= n_nodes) return;
    int beg = rp[r], end = rp[r + 1];
    float4 acc = make_float4(0.f, 0.f, 0.f, 0.f);
    size_t src_slice = (size_t)(hop - 1) * 64;
    for (int e = beg; e < end; ++e) {
        float2 ed = edges[e];
        int c = __float_as_int(ed.x);
        float v = ed.y;
        const float4* s = (const float4*)(out + (size_t)c * 256 + src_slice);
        float4 x = s[q];
        acc.x += v * x.x; acc.y += v * x.y; acc.z += v * x.z; acc.w += v * x.w;
    }
    float* dst = out + (size_t)r * 256 + (size_t)hop * 64;
    if (hop == 3) {
        f32x4 nv = {acc.x, acc.y, acc.z, acc.w};
        __builtin_nontemporal_store(nv, (f32x4*)dst + q);  // slice 3 never re-read
    } else {
        ((float4*)dst)[q] = acc;
    }
}

// ---------- fallback (ws too small): atomic scatter version ----------
__global__ void gc_init_out_full(const float4* __restrict__ user4,
                                 const float4* __restrict__ item4,
                                 float4* __restrict__ out4,
                                 int n_users, int n_nodes) {
    int tid = blockIdx.x * blockDim.x + threadIdx.x;
    if (tid >= n_nodes * 16) return;
    int node = tid >> 4;
    int q = tid & 15;
    float4 v = (node < n_users) ? user4[(size_t)node * 16 + q]
                                : item4[(size_t)(node - n_users) * 16 + q];
    float4 z = make_float4(0.f, 0.f, 0.f, 0.f);
    float4* p = out4 + (size_t)node * 64 + q;
    p[0] = v; p[16] = z; p[32] = z; p[48] = z;
}

__global__ void gc_spmm_atomic(const int* __restrict__ adj_row,
                               const int* __restrict__ adj_col,
                               const float* __restrict__ adj_val,
                               float* __restrict__ out, int hop, int nnz) {
    long long tid = (long long)blockIdx.x * blockDim.x + threadIdx.x;
    int e = (int)(tid >> 6);
    int j = (int)(tid & 63);
    if (e >= nnz) return;
    int r = adj_row[e];
    int c = adj_col[e];
    float v = adj_val[e];
    float x = out[(size_t)c * 256 + (size_t)(hop - 1) * 64 + j];
    unsafeAtomicAdd(&out[(size_t)r * 256 + (size_t)hop * 64 + j], v * x);
}

extern "C" void kernel_launch(void* const* d_in, const int* in_sizes, int n_in,
                              void* d_out, int out_size, void* d_ws, size_t ws_size,
                              hipStream_t stream) {
    const float* user_embed = (const float*)d_in[0];
    const float* item_embed = (const float*)d_in[1];
    const int*   adj_row    = (const int*)d_in[2];
    const int*   adj_col    = (const int*)d_in[3];
    const float* adj_val    = (const float*)d_in[4];
    const int n_users = in_sizes[0] / DFEAT;
    const int n_items = in_sizes[1] / DFEAT;
    const int n_nodes = n_users + n_items;
    const int nnz     = in_sizes[2];
    float* out = (float*)d_out;

    const int threads = 256;

    // ---- workspace carve-up ----
    size_t off = 0;
    auto carve = [&](size_t bytes) { size_t o = off; off = (off + bytes + 255) & ~(size_t)255; return o; };
    size_t o_cnt    = carve((size_t)n_nodes * 4);
    size_t o_rowptr = carve((size_t)(n_nodes + 1) * 4);
    size_t o_cursor = carve((size_t)n_nodes * 4);
    size_t o_bsums  = carve(256 * 4);
    size_t o_edges  = carve((size_t)nnz * 8);
    size_t needed = off;

    if (ws_size < needed) {
        int init_blocks = (n_nodes * 16 + threads - 1) / threads;
        hipLaunchKernelGGL(gc_init_out_full, dim3(init_blocks), dim3(threads), 0, stream,
                           (const float4*)user_embed, (const float4*)item_embed,
                           (float4*)out, n_users, n_nodes);
        long long spmm_total = (long long)nnz * 64;
        int spmm_blocks = (int)((spmm_total + threads - 1) / threads);
        for (int h = 1; h <= 3; ++h) {
            hipLaunchKernelGGL(gc_spmm_atomic, dim3(spmm_blocks), dim3(threads), 0, stream,
                               adj_row, adj_col, adj_val, out, h, nnz);
        }
        return;
    }

    char* ws = (char*)d_ws;
    int*    cnt    = (int*)(ws + o_cnt);
    int*    rowptr = (int*)(ws + o_rowptr);
    int*    cursor = (int*)(ws + o_cursor);
    int*    bsums  = (int*)(ws + o_bsums);
    float2* edges  = (float2*)(ws + o_edges);

    // ---- init hop-0 slice ----
    int init_blocks = (n_nodes * 16 + threads - 1) / threads;
    hipLaunchKernelGGL(gc_init_hop0, dim3(init_blocks), dim3(threads), 0, stream,
                       (const float4*)user_embed, (const float4*)item_embed,
                       (float4*)out, n_users, n_nodes);

    // ---- CSR build ----
    int n4 = (n_nodes + 3) / 4;   // cnt is carved 256B-aligned; int4 stores safe
    int zero_blocks = (n4 + threads - 1) / threads;
    hipLaunchKernelGGL(gc_zero, dim3(zero_blocks), dim3(threads), 0, stream,
                       (int4*)cnt, n4);
    int hist_blocks = (nnz + threads - 1) / threads;
    hipLaunchKernelGGL(gc_hist, dim3(hist_blocks), dim3(threads), 0, stream,
                       adj_row, cnt, nnz);
    int nb = (n_nodes + SCAN_EPB - 1) / SCAN_EPB;
    hipLaunchKernelGGL(gc_scan1, dim3(nb), dim3(SCAN_TPB), 0, stream,
                       cnt, rowptr, bsums, n_nodes);
    hipLaunchKernelGGL(gc_scan2, dim3(1), dim3(SCAN_TPB), 0, stream, bsums, nb);
    int scan3_blocks = (n_nodes + threads - 1) / threads;
    hipLaunchKernelGGL(gc_scan3, dim3(scan3_blocks), dim3(threads), 0, stream,
                       rowptr, bsums, rowptr, cursor, n_nodes, nnz);
    hipLaunchKernelGGL(gc_scatter, dim3(hist_blocks), dim3(threads), 0, stream,
                       adj_row, adj_col, adj_val, cursor, edges, nnz);

    // ---- 3 CSR hops, 16 lanes per row ----
    long long hop_threads = (long long)n_nodes * 16;
    int hop_blocks = (int)((hop_threads + threads - 1) / threads);
    for (int h = 1; h <= 3; ++h) {
        hipLaunchKernelGGL(gc_spmm_csr4, dim3(hop_blocks), dim3(threads), 0, stream,
                           rowptr, edges, out, h, n_nodes);
    }
}

// Round 6
// 440.251 us; speedup vs baseline: 1.1331x; 1.1331x over previous
//
#include <hip/hip_runtime.h>

// GraphConv 3-hop SpMM, CSR rebuilt per call.
// out layout: [N_NODES, 4, 64] fp32 (flat = node*256 + hop*64 + j).
// R6: hop kernel = 8 rows/wave (8 lanes x 32B), edge-unroll-2, scaled col
//     in edge record -> ~16 gathers in flight per wave (was 4).

#define DFEAT 64
#define SCAN_TPB 256
#define SCAN_EPB 2048  // 8 elements per thread

typedef float f32x4 __attribute__((ext_vector_type(4)));  // native vec for NT store

// ---------- zero the count array (int4 stores) ----------
__global__ void gc_zero(int4* __restrict__ p, int n4) {
    int i = blockIdx.x * blockDim.x + threadIdx.x;
    if (i < n4) p[i] = make_int4(0, 0, 0, 0);
}

// ---------- init: write hop-0 slice from embeddings ----------
__global__ void gc_init_hop0(const float4* __restrict__ user4,
                             const float4* __restrict__ item4,
                             float4* __restrict__ out4,
                             int n_users, int n_nodes) {
    int tid = blockIdx.x * blockDim.x + threadIdx.x;
    if (tid >= n_nodes * 16) return;
    int node = tid >> 4;
    int q = tid & 15;
    float4 v = (node < n_users) ? user4[(size_t)node * 16 + q]
                                : item4[(size_t)(node - n_users) * 16 + q];
    out4[(size_t)node * 64 + q] = v;   // hop 0 slot
}

// ---------- CSR build ----------
__global__ void gc_hist(const int* __restrict__ row, int* __restrict__ cnt, int nnz) {
    int i = blockIdx.x * blockDim.x + threadIdx.x;
    if (i < nnz) atomicAdd(&cnt[row[i]], 1);
}

__global__ void gc_scan1(const int* __restrict__ cnt, int* __restrict__ excl,
                         int* __restrict__ bsums, int n) {
    __shared__ int lds[SCAN_TPB];
    int t = threadIdx.x;
    int base = blockIdx.x * SCAN_EPB + t * 8;
    int v[8];
    int s = 0;
    for (int k = 0; k < 8; ++k) {
        int idx = base + k;
        v[k] = (idx < n) ? cnt[idx] : 0;
        s += v[k];
    }
    lds[t] = s;
    __syncthreads();
    for (int off = 1; off < SCAN_TPB; off <<= 1) {
        int u = (t >= off) ? lds[t - off] : 0;
        __syncthreads();
        lds[t] += u;
        __syncthreads();
    }
    int run = (t > 0) ? lds[t - 1] : 0;
    for (int k = 0; k < 8; ++k) {
        int idx = base + k;
        if (idx < n) excl[idx] = run;
        run += v[k];
    }
    if (t == SCAN_TPB - 1) bsums[blockIdx.x] = lds[SCAN_TPB - 1];
}

__global__ void gc_scan2(int* __restrict__ bsums, int nb) {
    __shared__ int lds[SCAN_TPB];
    int t = threadIdx.x;
    int v = (t < nb) ? bsums[t] : 0;
    lds[t] = v;
    __syncthreads();
    for (int off = 1; off < SCAN_TPB; off <<= 1) {
        int u = (t >= off) ? lds[t - off] : 0;
        __syncthreads();
        lds[t] += u;
        __syncthreads();
    }
    int excl = (t > 0) ? lds[t - 1] : 0;
    if (t < nb) bsums[t] = excl;
}

__global__ void gc_scan3(int* __restrict__ excl, const int* __restrict__ bsums,
                         int* __restrict__ row_ptr, int* __restrict__ cursor,
                         int n, int nnz) {
    int i = blockIdx.x * blockDim.x + threadIdx.x;
    if (i < n) {
        int v = excl[i] + bsums[i / SCAN_EPB];
        row_ptr[i] = v;
        cursor[i] = v;
    }
    if (i == 0) row_ptr[n] = nnz;
}

// Scatter edges into CSR order; record = (col*64 as int bits, val).
// col*64 = source node's float4-quad base index (< 2^25, exact).
__global__ void gc_scatter(const int* __restrict__ row, const int* __restrict__ col,
                           const float* __restrict__ val,
                           int* __restrict__ cursor, float2* __restrict__ edges,
                           int nnz) {
    int i = blockIdx.x * blockDim.x + threadIdx.x;
    if (i >= nnz) return;
    int r = row[i];
    int pos = atomicAdd(&cursor[r], 1);
    edges[pos] = make_float2(__int_as_float(col[i] << 6), val[i]);
}

// ---------- hop: 8 lanes (2x float4 each) per row; 8 rows per wave;
//             edge loop unrolled by 2 for gather MLP ----------
__global__ void gc_spmm_csr8(const int* __restrict__ rp,
                             const float2* __restrict__ edges,
                             float* __restrict__ out, int hop, int n_nodes) {
    int tid = blockIdx.x * blockDim.x + threadIdx.x;
    int l = tid & 7;            // lane within row (handles 8 floats = 2 quads)
    int r = tid >> 3;           // row
    if (r >= n_nodes) return;
    int beg = rp[r], end = rp[r + 1];
    const float4* out4 = (const float4*)out;
    int lane_off = (hop - 1) * 16 + l * 2;   // quad offset within source node
    float4 a0 = make_float4(0.f, 0.f, 0.f, 0.f);
    float4 a1 = make_float4(0.f, 0.f, 0.f, 0.f);
    int e = beg;
    for (; e + 2 <= end; e += 2) {
        float2 e0 = edges[e];
        float2 e1 = edges[e + 1];
        int i0 = __float_as_int(e0.x) + lane_off;
        int i1 = __float_as_int(e1.x) + lane_off;
        float4 x0a = out4[i0];
        float4 x0b = out4[i0 + 1];
        float4 x1a = out4[i1];
        float4 x1b = out4[i1 + 1];
        float v0 = e0.y, v1 = e1.y;
        a0.x += v0 * x0a.x; a0.y += v0 * x0a.y; a0.z += v0 * x0a.z; a0.w += v0 * x0a.w;
        a1.x += v0 * x0b.x; a1.y += v0 * x0b.y; a1.z += v0 * x0b.z; a1.w += v0 * x0b.w;
        a0.x += v1 * x1a.x; a0.y += v1 * x1a.y; a0.z += v1 * x1a.z; a0.w += v1 * x1a.w;
        a1.x += v1 * x1b.x; a1.y += v1 * x1b.y; a1.z += v1 * x1b.z; a1.w += v1 * x1b.w;
    }
    if (e < end) {
        float2 e0 = edges[e];
        int i0 = __float_as_int(e0.x) + lane_off;
        float4 x0a = out4[i0];
        float4 x0b = out4[i0 + 1];
        float v0 = e0.y;
        a0.x += v0 * x0a.x; a0.y += v0 * x0a.y; a0.z += v0 * x0a.z; a0.w += v0 * x0a.w;
        a1.x += v0 * x0b.x; a1.y += v0 * x0b.y; a1.z += v0 * x0b.z; a1.w += v0 * x0b.w;
    }
    size_t dq = (size_t)r * 64 + (size_t)hop * 16 + l * 2;
    float4* o4 = (float4*)out;
    if (hop == 3) {
        f32x4 n0 = {a0.x, a0.y, a0.z, a0.w};
        f32x4 n1 = {a1.x, a1.y, a1.z, a1.w};
        __builtin_nontemporal_store(n0, (f32x4*)o4 + dq);       // slice 3 never re-read
        __builtin_nontemporal_store(n1, (f32x4*)o4 + dq + 1);
    } else {
        o4[dq] = a0;
        o4[dq + 1] = a1;
    }
}

// ---------- fallback (ws too small): atomic scatter version ----------
__global__ void gc_init_out_full(const float4* __restrict__ user4,
                                 const float4* __restrict__ item4,
                                 float4* __restrict__ out4,
                                 int n_users, int n_nodes) {
    int tid = blockIdx.x * blockDim.x + threadIdx.x;
    if (tid >= n_nodes * 16) return;
    int node = tid >> 4;
    int q = tid & 15;
    float4 v = (node < n_users) ? user4[(size_t)node * 16 + q]
                                : item4[(size_t)(node - n_users) * 16 + q];
    float4 z = make_float4(0.f, 0.f, 0.f, 0.f);
    float4* p = out4 + (size_t)node * 64 + q;
    p[0] = v; p[16] = z; p[32] = z; p[48] = z;
}

__global__ void gc_spmm_atomic(const int* __restrict__ adj_row,
                               const int* __restrict__ adj_col,
                               const float* __restrict__ adj_val,
                               float* __restrict__ out, int hop, int nnz) {
    long long tid = (long long)blockIdx.x * blockDim.x + threadIdx.x;
    int e = (int)(tid >> 6);
    int j = (int)(tid & 63);
    if (e >= nnz) return;
    int r = adj_row[e];
    int c = adj_col[e];
    float v = adj_val[e];
    float x = out[(size_t)c * 256 + (size_t)(hop - 1) * 64 + j];
    unsafeAtomicAdd(&out[(size_t)r * 256 + (size_t)hop * 64 + j], v * x);
}

extern "C" void kernel_launch(void* const* d_in, const int* in_sizes, int n_in,
                              void* d_out, int out_size, void* d_ws, size_t ws_size,
                              hipStream_t stream) {
    const float* user_embed = (const float*)d_in[0];
    const float* item_embed = (const float*)d_in[1];
    const int*   adj_row    = (const int*)d_in[2];
    const int*   adj_col    = (const int*)d_in[3];
    const float* adj_val    = (const float*)d_in[4];
    const int n_users = in_sizes[0] / DFEAT;
    const int n_items = in_sizes[1] / DFEAT;
    const int n_nodes = n_users + n_items;
    const int nnz     = in_sizes[2];
    float* out = (float*)d_out;

    const int threads = 256;

    // ---- workspace carve-up ----
    size_t off = 0;
    auto carve = [&](size_t bytes) { size_t o = off; off = (off + bytes + 255) & ~(size_t)255; return o; };
    size_t o_cnt    = carve((size_t)n_nodes * 4);
    size_t o_rowptr = carve((size_t)(n_nodes + 1) * 4);
    size_t o_cursor = carve((size_t)n_nodes * 4);
    size_t o_bsums  = carve(256 * 4);
    size_t o_edges  = carve((size_t)nnz * 8);
    size_t needed = off;

    if (ws_size < needed) {
        int init_blocks = (n_nodes * 16 + threads - 1) / threads;
        hipLaunchKernelGGL(gc_init_out_full, dim3(init_blocks), dim3(threads), 0, stream,
                           (const float4*)user_embed, (const float4*)item_embed,
                           (float4*)out, n_users, n_nodes);
        long long spmm_total = (long long)nnz * 64;
        int spmm_blocks = (int)((spmm_total + threads - 1) / threads);
        for (int h = 1; h <= 3; ++h) {
            hipLaunchKernelGGL(gc_spmm_atomic, dim3(spmm_blocks), dim3(threads), 0, stream,
                               adj_row, adj_col, adj_val, out, h, nnz);
        }
        return;
    }

    char* ws = (char*)d_ws;
    int*    cnt    = (int*)(ws + o_cnt);
    int*    rowptr = (int*)(ws + o_rowptr);
    int*    cursor = (int*)(ws + o_cursor);
    int*    bsums  = (int*)(ws + o_bsums);
    float2* edges  = (float2*)(ws + o_edges);

    // ---- init hop-0 slice ----
    int init_blocks = (n_nodes * 16 + threads - 1) / threads;
    hipLaunchKernelGGL(gc_init_hop0, dim3(init_blocks), dim3(threads), 0, stream,
                       (const float4*)user_embed, (const float4*)item_embed,
                       (float4*)out, n_users, n_nodes);

    // ---- CSR build ----
    int n4 = (n_nodes + 3) / 4;   // cnt is carved 256B-aligned; int4 stores safe
    int zero_blocks = (n4 + threads - 1) / threads;
    hipLaunchKernelGGL(gc_zero, dim3(zero_blocks), dim3(threads), 0, stream,
                       (int4*)cnt, n4);
    int hist_blocks = (nnz + threads - 1) / threads;
    hipLaunchKernelGGL(gc_hist, dim3(hist_blocks), dim3(threads), 0, stream,
                       adj_row, cnt, nnz);
    int nb = (n_nodes + SCAN_EPB - 1) / SCAN_EPB;
    hipLaunchKernelGGL(gc_scan1, dim3(nb), dim3(SCAN_TPB), 0, stream,
                       cnt, rowptr, bsums, n_nodes);
    hipLaunchKernelGGL(gc_scan2, dim3(1), dim3(SCAN_TPB), 0, stream, bsums, nb);
    int scan3_blocks = (n_nodes + threads - 1) / threads;
    hipLaunchKernelGGL(gc_scan3, dim3(scan3_blocks), dim3(threads), 0, stream,
                       rowptr, bsums, rowptr, cursor, n_nodes, nnz);
    hipLaunchKernelGGL(gc_scatter, dim3(hist_blocks), dim3(threads), 0, stream,
                       adj_row, adj_col, adj_val, cursor, edges, nnz);

    // ---- 3 CSR hops, 8 lanes per row ----
    long long hop_threads = (long long)n_nodes * 8;
    int hop_blocks = (int)((hop_threads + threads - 1) / threads);
    for (int h = 1; h <= 3; ++h) {
        hipLaunchKernelGGL(gc_spmm_csr8, dim3(hop_blocks), dim3(threads), 0, stream,
                           rowptr, edges, out, h, n_nodes);
    }
}